// Round 1
// baseline (498.169 us; speedup 1.0000x reference)
//
#include <hip/hip_runtime.h>
#include <hip/hip_bf16.h>
#include <cstdint>

typedef __attribute__((ext_vector_type(8))) short bf16x8;
typedef __attribute__((ext_vector_type(4))) float f32x4;

#define MFMA16(a, b, c) __builtin_amdgcn_mfma_f32_16x16x32_bf16((a), (b), (c), 0, 0, 0)

__device__ __forceinline__ ushort f2bf(float x) {
  union { float f; uint32_t u; } c; c.f = x;
  uint32_t r = (c.u + 0x7FFFu + ((c.u >> 16) & 1u)) >> 16;
  return (ushort)r;
}

__device__ __forceinline__ void gload_lds16(const ushort* g, ushort* l) {
  __builtin_amdgcn_global_load_lds((__attribute__((address_space(1))) void*)g,
                                   (__attribute__((address_space(3))) void*)l, 16, 0, 0);
}

// Stage a 128x64 bf16 tile (rows x k) from global (row stride = ld elements) into
// linear LDS [128][64]. Source column bytes are XOR-swizzled by ((row&7)<<4) so that
// swizzled ds_read_b128 on the consumer side is bank-conflict-free (guide rule #21).
__device__ __forceinline__ void stage128x64(const ushort* __restrict__ tileBase, int ld,
                                            ushort* lds, int wid, int lane) {
#pragma unroll
  for (int q = 0; q < 4; q++) {
    int r = wid * 32 + q * 8 + (lane >> 3);
    int cb = ((lane & 7) * 16) ^ ((r & 7) << 4);  // swizzled source byte offset in row
    gload_lds16(tileBase + (long)r * ld + (cb >> 1), lds + (wid * 32 + q * 8) * 64);
  }
}

__device__ __forceinline__ bf16x8 frag_read(const ushort* lds, int r, int kb) {
  int off = r * 128 + (kb ^ ((r & 7) << 4));
  return *(const bf16x8*)((const char*)lds + off);
}

// ---------------- f32 -> bf16 conversion ----------------
__global__ void cvt_kernel(const float* __restrict__ in, ushort* __restrict__ out, long n4) {
  long stride = (long)gridDim.x * blockDim.x;
  for (long g = (long)blockIdx.x * blockDim.x + threadIdx.x; g < n4; g += stride) {
    float4 v = ((const float4*)in)[g];
    ((ushort4*)out)[g] = make_ushort4(f2bf(v.x), f2bf(v.y), f2bf(v.z), f2bf(v.w));
  }
}

// ---------------- top-k (k=2, E=16, B=8) ----------------
__global__ void topk_kernel(const float* __restrict__ probs, int* __restrict__ ids,
                            float* __restrict__ pr) {
  int b = threadIdx.x;
  if (b < 8) {
    const float* p = probs + b * 16;
    float v0 = -1e30f, v1 = -1e30f; int i0 = 0, i1 = 0;
    for (int e = 0; e < 16; e++) {
      float v = p[e];
      if (v > v0) { v1 = v0; i1 = i0; v0 = v; i0 = e; }
      else if (v > v1) { v1 = v; i1 = e; }
    }
    float s = 1.0f / (v0 + v1 + 1e-8f);
    ids[b * 2 + 0] = i0; ids[b * 2 + 1] = i1;
    pr[b * 2 + 0] = v0 * s; pr[b * 2 + 1] = v1 * s;
  }
}

// ---------------- fused gate/up GEMM + SiLU*up -> bf16 G ----------------
// C1[s,i] = sum_h X[s,h]*Wg[eid][i,h]; C2 same with Wu; G = silu(C1)*C2
__global__ __launch_bounds__(256) void gateup_kernel(
    const ushort* __restrict__ Hb, const ushort* __restrict__ Wg,
    const ushort* __restrict__ Wu, const int* __restrict__ ids,
    ushort* __restrict__ G) {
  constexpr int Hd = 512, I = 2048, S = 512;
  const int p = blockIdx.z, b = p >> 1;
  const int eid = ids[p];
  const ushort* A  = Hb + (long)b * S * Hd;
  const ushort* B1 = Wg + (long)eid * I * Hd;
  const ushort* B2 = Wu + (long)eid * I * Hd;
  const int row0 = blockIdx.x * 128;
  const int col0 = blockIdx.y * 128;

  __shared__ ushort As[128 * 64], B1s[128 * 64], B2s[128 * 64];

  const int tid = threadIdx.x, wid = tid >> 6, lane = tid & 63;
  const int wr = wid >> 1, wc = wid & 1;

  f32x4 acc1[4][4] = {};
  f32x4 acc2[4][4] = {};

  for (int k0 = 0; k0 < Hd; k0 += 64) {
    stage128x64(A  + (long)row0 * Hd + k0, Hd, As,  wid, lane);
    stage128x64(B1 + (long)col0 * Hd + k0, Hd, B1s, wid, lane);
    stage128x64(B2 + (long)col0 * Hd + k0, Hd, B2s, wid, lane);
    __syncthreads();
#pragma unroll
    for (int t = 0; t < 2; t++) {
      const int kb = t * 64 + ((lane >> 4) * 16);
      bf16x8 av[4], b1v[4], b2v[4];
#pragma unroll
      for (int i = 0; i < 4; i++) av[i] = frag_read(As, wr * 64 + i * 16 + (lane & 15), kb);
#pragma unroll
      for (int j = 0; j < 4; j++) {
        b1v[j] = frag_read(B1s, wc * 64 + j * 16 + (lane & 15), kb);
        b2v[j] = frag_read(B2s, wc * 64 + j * 16 + (lane & 15), kb);
      }
#pragma unroll
      for (int i = 0; i < 4; i++)
#pragma unroll
        for (int j = 0; j < 4; j++) {
          acc1[i][j] = MFMA16(av[i], b1v[j], acc1[i][j]);
          acc2[i][j] = MFMA16(av[i], b2v[j], acc2[i][j]);
        }
    }
    __syncthreads();
  }

  ushort* Gout = G + (long)p * S * I;
#pragma unroll
  for (int i = 0; i < 4; i++) {
    int rbase = row0 + wr * 64 + i * 16 + ((lane >> 4) * 4);
#pragma unroll
    for (int j = 0; j < 4; j++) {
      int c = col0 + wc * 64 + j * 16 + (lane & 15);
#pragma unroll
      for (int q = 0; q < 4; q++) {
        float g = acc1[i][j][q], u = acc2[i][j][q];
        float sg = g / (1.0f + __expf(-g));
        Gout[(long)(rbase + q) * I + c] = f2bf(sg * u);
      }
    }
  }
}

// ---------------- generic bf16 GEMM (A[M][K] x Bt[N][K]) -> f32 out ----------------
__global__ __launch_bounds__(256) void gemm_bt_f32(
    const ushort* __restrict__ Abase, long aStrideZ,
    const ushort* __restrict__ Bbase, long bStrideZ, const int* __restrict__ bIds,
    float* __restrict__ Obase, long oStrideZ, int Kdim, int ldc) {
  const int z = blockIdx.z;
  const ushort* A = Abase + (long)z * aStrideZ;
  const ushort* B = Bbase + (long)(bIds ? bIds[z] : 0) * bStrideZ;
  float* Out = Obase + (long)z * oStrideZ;
  const int row0 = blockIdx.x * 128, col0 = blockIdx.y * 128;

  __shared__ ushort As[128 * 64], Bs[128 * 64];
  const int tid = threadIdx.x, wid = tid >> 6, lane = tid & 63;
  const int wr = wid >> 1, wc = wid & 1;

  f32x4 acc[4][4] = {};

  for (int k0 = 0; k0 < Kdim; k0 += 64) {
    stage128x64(A + (long)row0 * Kdim + k0, Kdim, As, wid, lane);
    stage128x64(B + (long)col0 * Kdim + k0, Kdim, Bs, wid, lane);
    __syncthreads();
#pragma unroll
    for (int t = 0; t < 2; t++) {
      const int kb = t * 64 + ((lane >> 4) * 16);
      bf16x8 av[4], bv[4];
#pragma unroll
      for (int i = 0; i < 4; i++) av[i] = frag_read(As, wr * 64 + i * 16 + (lane & 15), kb);
#pragma unroll
      for (int j = 0; j < 4; j++) bv[j] = frag_read(Bs, wc * 64 + j * 16 + (lane & 15), kb);
#pragma unroll
      for (int i = 0; i < 4; i++)
#pragma unroll
        for (int j = 0; j < 4; j++)
          acc[i][j] = MFMA16(av[i], bv[j], acc[i][j]);
    }
    __syncthreads();
  }

#pragma unroll
  for (int i = 0; i < 4; i++) {
    int rbase = row0 + wr * 64 + i * 16 + ((lane >> 4) * 4);
#pragma unroll
    for (int j = 0; j < 4; j++) {
      int c = col0 + wc * 64 + j * 16 + (lane & 15);
#pragma unroll
      for (int q = 0; q < 4; q++)
        Out[(long)(rbase + q) * ldc + c] = acc[i][j][q];
    }
  }
}

// ---------------- weighted combine of the two expert outputs -> bf16 ----------------
__global__ void combine_kernel(const float* __restrict__ Opair, const float* __restrict__ pr,
                               ushort* __restrict__ Cb) {
  const long n4 = (8L * 512 * 512) / 4;
  long stride = (long)gridDim.x * blockDim.x;
  for (long g = (long)blockIdx.x * blockDim.x + threadIdx.x; g < n4; g += stride) {
    long e = g * 4;
    int b = (int)(e >> 18);           // 512*512 = 2^18 per batch
    long r4 = (e & 262143) >> 2;
    float4 a = ((const float4*)(Opair + ((long)(2 * b) << 18)))[r4];
    float4 c = ((const float4*)(Opair + ((long)(2 * b + 1) << 18)))[r4];
    float p0 = pr[2 * b], p1 = pr[2 * b + 1];
    ((ushort4*)Cb)[g] = make_ushort4(f2bf(p0 * a.x + p1 * c.x), f2bf(p0 * a.y + p1 * c.y),
                                     f2bf(p0 * a.z + p1 * c.z), f2bf(p0 * a.w + p1 * c.w));
  }
}

extern "C" void kernel_launch(void* const* d_in, const int* in_sizes, int n_in,
                              void* d_out, int out_size, void* d_ws, size_t ws_size,
                              hipStream_t stream) {
  const float* hidden = (const float*)d_in[0];   // [8,512,512]
  const float* eprobs = (const float*)d_in[1];   // [8,16]
  const float* Wg     = (const float*)d_in[2];   // [16,2048,512]
  const float* Wu     = (const float*)d_in[3];   // [16,2048,512]
  const float* Wd     = (const float*)d_in[4];   // [16,512,2048]
  const float* Wout   = (const float*)d_in[5];   // [32000,512]
  float* out = (float*)d_out;                    // [8,512,32000] f32

  char* ws = (char*)d_ws;
  int*    t_ids = (int*)ws;                    // 16 ints
  float*  t_pr  = (float*)(ws + 64);           // 16 floats
  ushort* h_bf  = (ushort*)(ws + 256);         // 8*512*512
  ushort* wg_bf = h_bf  + 2097152L;            // 16*2048*512
  ushort* wu_bf = wg_bf + 16777216L;
  ushort* wd_bf = wu_bf + 16777216L;
  ushort* wo_bf = wd_bf + 16777216L;           // 32000*512
  ushort* Gbuf  = wo_bf + 16384000L;           // 16*512*2048 bf16
  float*  Opair = (float*)(Gbuf + 16777216L);  // 16*512*512 f32
  ushort* Cb    = (ushort*)(Opair + 4194304L); // 8*512*512 bf16
  // total ~192.2 MB of d_ws

  hipLaunchKernelGGL(cvt_kernel, dim3(2048), dim3(256), 0, stream, hidden, h_bf, 2097152L / 4);
  hipLaunchKernelGGL(cvt_kernel, dim3(4096), dim3(256), 0, stream, Wg, wg_bf, 16777216L / 4);
  hipLaunchKernelGGL(cvt_kernel, dim3(4096), dim3(256), 0, stream, Wu, wu_bf, 16777216L / 4);
  hipLaunchKernelGGL(cvt_kernel, dim3(4096), dim3(256), 0, stream, Wd, wd_bf, 16777216L / 4);
  hipLaunchKernelGGL(cvt_kernel, dim3(4096), dim3(256), 0, stream, Wout, wo_bf, 16384000L / 4);
  hipLaunchKernelGGL(topk_kernel, dim3(1), dim3(64), 0, stream, eprobs, t_ids, t_pr);

  // gate/up: grid (S/128, I/128, B*topk)
  hipLaunchKernelGGL(gateup_kernel, dim3(4, 16, 16), dim3(256), 0, stream,
                     h_bf, wg_bf, wu_bf, t_ids, Gbuf);
  // down: C[p][s,h] = G[p] x Wd[eid]^T   (K = 2048)
  hipLaunchKernelGGL(gemm_bt_f32, dim3(4, 4, 16), dim3(256), 0, stream,
                     Gbuf, (long)512 * 2048, wd_bf, (long)512 * 2048, t_ids,
                     Opair, (long)512 * 512, 2048, 512);
  hipLaunchKernelGGL(combine_kernel, dim3(1024), dim3(256), 0, stream, Opair, t_pr, Cb);
  // output projection: [4096,512] x [32000,512]^T  (K = 512)
  hipLaunchKernelGGL(gemm_bt_f32, dim3(32, 250, 1), dim3(256), 0, stream,
                     Cb, 0L, wo_bf, 0L, (const int*)nullptr,
                     out, 0L, 512, 32000);
}

// Round 2
// 442.305 us; speedup vs baseline: 1.1263x; 1.1263x over previous
//
#include <hip/hip_runtime.h>
#include <hip/hip_bf16.h>
#include <cstdint>

typedef __attribute__((ext_vector_type(8))) short bf16x8;
typedef __attribute__((ext_vector_type(4))) float f32x4;

#define MFMA16(a, b, c) __builtin_amdgcn_mfma_f32_16x16x32_bf16((a), (b), (c), 0, 0, 0)

__device__ __forceinline__ ushort f2bf(float x) {
  union { float f; uint32_t u; } c; c.f = x;
  uint32_t r = (c.u + 0x7FFFu + ((c.u >> 16) & 1u)) >> 16;
  return (ushort)r;
}

__device__ __forceinline__ void gload_lds16(const ushort* g, ushort* l) {
  __builtin_amdgcn_global_load_lds((__attribute__((address_space(1))) void*)g,
                                   (__attribute__((address_space(3))) void*)l, 16, 0, 0);
}

// Stage (NW*INSTR*8) x 64 bf16 tile from global (row stride ld elems) into linear LDS
// [rows][64]. Source 16B-slot is XOR-swizzled by (row&7) so swizzled ds_read_b128 on the
// consumer side is ~2-way (free) bank-conflicted (guide rule #21: linear dest +
// inverse-swizzled source + same swizzle on read).
template <int NW, int INSTR>
__device__ __forceinline__ void stageT(const ushort* __restrict__ tileBase, int ld,
                                       ushort* lds, int wid, int lane) {
#pragma unroll
  for (int q = 0; q < INSTR; q++) {
    int r = (wid * INSTR + q) * 8 + (lane >> 3);
    int cb = ((lane & 7) * 16) ^ ((r & 7) << 4);  // swizzled source byte offset in row
    gload_lds16(tileBase + (long)r * ld + (cb >> 1), lds + (wid * INSTR + q) * 512);
  }
}

__device__ __forceinline__ bf16x8 frag_read(const ushort* lds, int r, int kb) {
  int off = r * 128 + (kb ^ ((r & 7) << 4));
  return *(const bf16x8*)((const char*)lds + off);
}

// ---------------- f32 -> bf16 conversion ----------------
__global__ void cvt_kernel(const float* __restrict__ in, ushort* __restrict__ out, long n4) {
  long stride = (long)gridDim.x * blockDim.x;
  for (long g = (long)blockIdx.x * blockDim.x + threadIdx.x; g < n4; g += stride) {
    float4 v = ((const float4*)in)[g];
    ((ushort4*)out)[g] = make_ushort4(f2bf(v.x), f2bf(v.y), f2bf(v.z), f2bf(v.w));
  }
}

// ---------------- top-k (k=2, E=16, B=8) ----------------
__global__ void topk_kernel(const float* __restrict__ probs, int* __restrict__ ids,
                            float* __restrict__ pr) {
  int b = threadIdx.x;
  if (b < 8) {
    const float* p = probs + b * 16;
    float v0 = -1e30f, v1 = -1e30f; int i0 = 0, i1 = 0;
    for (int e = 0; e < 16; e++) {
      float v = p[e];
      if (v > v0) { v1 = v0; i1 = i0; v0 = v; i0 = e; }
      else if (v > v1) { v1 = v; i1 = e; }
    }
    float s = 1.0f / (v0 + v1 + 1e-8f);
    ids[b * 2 + 0] = i0; ids[b * 2 + 1] = i1;
    pr[b * 2 + 0] = v0 * s; pr[b * 2 + 1] = v1 * s;
  }
}

// ---------------- fused gate/up, BM=256 x BN=128, dual-B, 8 waves, pipelined ----------------
__global__ __launch_bounds__(512, 2) void gateup256(
    const ushort* __restrict__ Hb, const ushort* __restrict__ Wg,
    const ushort* __restrict__ Wu, const int* __restrict__ ids,
    ushort* __restrict__ G) {
  constexpr int Hd = 512, I = 2048, S = 512, NT = Hd / 64;
  __shared__ ushort As[2][256 * 64], B1s[2][128 * 64], B2s[2][128 * 64];  // 128 KiB

  // XCD swizzle over 512 blocks; decompose so one XCD chunk stays within few (p) groups
  int wg = blockIdx.x;
  int swz = (wg & 7) * 64 + (wg >> 3);
  int p = swz >> 5;                 // 16 (batch,k) pairs
  int r5 = swz & 31;
  int rowT = r5 & 1, colT = r5 >> 1;
  const int b = p >> 1, eid = ids[p];
  const int row0 = rowT * 256, col0 = colT * 128;
  const ushort* Ab  = Hb + (long)b * S * Hd + (long)row0 * Hd;
  const ushort* B1b = Wg + (long)eid * I * Hd + (long)col0 * Hd;
  const ushort* B2b = Wu + (long)eid * I * Hd + (long)col0 * Hd;

  const int tid = threadIdx.x, wid = tid >> 6, lane = tid & 63;
  const int wr = wid >> 2, wc = wid & 3;   // wave tile: 128 rows x 32 cols

  f32x4 acc1[8][2] = {};
  f32x4 acc2[8][2] = {};

  stageT<8, 4>(Ab, Hd, As[0], wid, lane);
  stageT<8, 2>(B1b, Hd, B1s[0], wid, lane);
  stageT<8, 2>(B2b, Hd, B2s[0], wid, lane);

  for (int kt = 0; kt < NT; kt++) {
    __syncthreads();  // drains vmcnt(0): tile kt loads issued ~3 sub-phases ago
    const int cur = kt & 1;
    const ushort* as = As[cur];
    const ushort* b1 = B1s[cur];
    const ushort* b2 = B2s[cur];
    if (kt + 1 < NT) stageT<8, 4>(Ab + (kt + 1) * 64, Hd, As[cur ^ 1], wid, lane);
#pragma unroll
    for (int ks = 0; ks < 2; ks++) {
      const int kb = ks * 64 + ((lane >> 4) * 16);
      bf16x8 av[8];
#pragma unroll
      for (int i = 0; i < 8; i++) av[i] = frag_read(as, wr * 128 + i * 16 + (lane & 15), kb);
      if (ks == 0 && kt + 1 < NT) {
        stageT<8, 2>(B1b + (kt + 1) * 64, Hd, B1s[cur ^ 1], wid, lane);
        stageT<8, 2>(B2b + (kt + 1) * 64, Hd, B2s[cur ^ 1], wid, lane);
      }
      bf16x8 b1v[2], b2v[2];
#pragma unroll
      for (int j = 0; j < 2; j++) b1v[j] = frag_read(b1, wc * 32 + j * 16 + (lane & 15), kb);
      __builtin_amdgcn_s_setprio(1);
#pragma unroll
      for (int i = 0; i < 8; i++)
#pragma unroll
        for (int j = 0; j < 2; j++) acc1[i][j] = MFMA16(av[i], b1v[j], acc1[i][j]);
      __builtin_amdgcn_s_setprio(0);
#pragma unroll
      for (int j = 0; j < 2; j++) b2v[j] = frag_read(b2, wc * 32 + j * 16 + (lane & 15), kb);
      __builtin_amdgcn_s_setprio(1);
#pragma unroll
      for (int i = 0; i < 8; i++)
#pragma unroll
        for (int j = 0; j < 2; j++) acc2[i][j] = MFMA16(av[i], b2v[j], acc2[i][j]);
      __builtin_amdgcn_s_setprio(0);
    }
  }

  ushort* Gout = G + (long)p * S * I;
#pragma unroll
  for (int i = 0; i < 8; i++) {
    int r = row0 + wr * 128 + i * 16 + ((lane >> 4) * 4);
#pragma unroll
    for (int j = 0; j < 2; j++) {
      int c = col0 + wc * 32 + j * 16 + (lane & 15);
#pragma unroll
      for (int q = 0; q < 4; q++) {
        float g = acc1[i][j][q], u = acc2[i][j][q];
        float sg = g / (1.0f + __expf(-g));
        Gout[(long)(r + q) * I + c] = f2bf(sg * u);
      }
    }
  }
}

// ---------------- final projection, 256x256, 8 waves, pipelined ----------------
__global__ __launch_bounds__(512, 2) void gemm256_final(
    const ushort* __restrict__ A,   // [4096][512] bf16 (combined)
    const ushort* __restrict__ B,   // [32000][512] bf16 (Wout)
    float* __restrict__ Out) {      // [4096][32000] f32
  constexpr int K = 512, NT = K / 64, LDC = 32000;
  __shared__ ushort As[2][256 * 64], Bs[2][256 * 64];  // 128 KiB

  // XCD swizzle: nwg = 2000, chunk = 250/XCD; within chunk sweep row tiles per col tile
  int wg = blockIdx.x;
  int swz = (wg & 7) * 250 + (wg >> 3);
  const int colT = swz / 16, rowT = swz % 16;
  const int row0 = rowT * 256, col0 = colT * 256;

  const int tid = threadIdx.x, wid = tid >> 6, lane = tid & 63;
  const int wr = wid >> 2, wc = wid & 3;   // wave tile: 128 rows x 64 cols

  f32x4 acc[8][4] = {};
  const ushort* Ab = A + (long)row0 * K;
  const ushort* Bb = B + (long)col0 * K;

  stageT<8, 4>(Ab, K, As[0], wid, lane);
  stageT<8, 4>(Bb, K, Bs[0], wid, lane);

  for (int kt = 0; kt < NT; kt++) {
    __syncthreads();
    const int cur = kt & 1;
    const ushort* as = As[cur];
    const ushort* bs = Bs[cur];
    if (kt + 1 < NT) stageT<8, 4>(Ab + (kt + 1) * 64, K, As[cur ^ 1], wid, lane);
#pragma unroll
    for (int ks = 0; ks < 2; ks++) {
      const int kb = ks * 64 + ((lane >> 4) * 16);
      bf16x8 av[8];
#pragma unroll
      for (int i = 0; i < 8; i++) av[i] = frag_read(as, wr * 128 + i * 16 + (lane & 15), kb);
      if (ks == 0 && kt + 1 < NT) stageT<8, 4>(Bb + (kt + 1) * 64, K, Bs[cur ^ 1], wid, lane);
#pragma unroll
      for (int jh = 0; jh < 2; jh++) {
        bf16x8 bv[2];
#pragma unroll
        for (int j2 = 0; j2 < 2; j2++)
          bv[j2] = frag_read(bs, wc * 64 + jh * 32 + j2 * 16 + (lane & 15), kb);
        __builtin_amdgcn_s_setprio(1);
#pragma unroll
        for (int i = 0; i < 8; i++)
#pragma unroll
          for (int j2 = 0; j2 < 2; j2++)
            acc[i][jh * 2 + j2] = MFMA16(av[i], bv[j2], acc[i][jh * 2 + j2]);
        __builtin_amdgcn_s_setprio(0);
      }
    }
  }

#pragma unroll
  for (int i = 0; i < 8; i++) {
    int r = row0 + wr * 128 + i * 16 + ((lane >> 4) * 4);
#pragma unroll
    for (int j = 0; j < 4; j++) {
      int c = col0 + wc * 64 + j * 16 + (lane & 15);
#pragma unroll
      for (int q = 0; q < 4; q++)
        Out[(long)(r + q) * LDC + c] = acc[i][j][q];
    }
  }
}

// ---------------- generic bf16 GEMM 128x128 (down projection) ----------------
__global__ __launch_bounds__(256) void gemm_bt_f32(
    const ushort* __restrict__ Abase, long aStrideZ,
    const ushort* __restrict__ Bbase, long bStrideZ, const int* __restrict__ bIds,
    float* __restrict__ Obase, long oStrideZ, int Kdim, int ldc) {
  const int z = blockIdx.z;
  const ushort* A = Abase + (long)z * aStrideZ;
  const ushort* B = Bbase + (long)(bIds ? bIds[z] : 0) * bStrideZ;
  float* Out = Obase + (long)z * oStrideZ;
  const int row0 = blockIdx.x * 128, col0 = blockIdx.y * 128;

  __shared__ ushort As[2][128 * 64], Bs[2][128 * 64];
  const int tid = threadIdx.x, wid = tid >> 6, lane = tid & 63;
  const int wr = wid >> 1, wc = wid & 1;

  f32x4 acc[4][4] = {};
  const ushort* Ab = A + (long)row0 * Kdim;
  const ushort* Bb = B + (long)col0 * Kdim;
  const int NT = Kdim / 64;

  stageT<4, 4>(Ab, Kdim, As[0], wid, lane);
  stageT<4, 4>(Bb, Kdim, Bs[0], wid, lane);

  for (int kt = 0; kt < NT; kt++) {
    __syncthreads();
    const int cur = kt & 1;
    const ushort* as = As[cur];
    const ushort* bs = Bs[cur];
    if (kt + 1 < NT) stageT<4, 4>(Ab + (kt + 1) * 64, Kdim, As[cur ^ 1], wid, lane);
#pragma unroll
    for (int t = 0; t < 2; t++) {
      const int kb = t * 64 + ((lane >> 4) * 16);
      bf16x8 av[4], bv[4];
#pragma unroll
      for (int i = 0; i < 4; i++) av[i] = frag_read(as, wr * 64 + i * 16 + (lane & 15), kb);
      if (t == 0 && kt + 1 < NT) stageT<4, 4>(Bb + (kt + 1) * 64, Kdim, Bs[cur ^ 1], wid, lane);
#pragma unroll
      for (int j = 0; j < 4; j++) bv[j] = frag_read(bs, wc * 64 + j * 16 + (lane & 15), kb);
      __builtin_amdgcn_s_setprio(1);
#pragma unroll
      for (int i = 0; i < 4; i++)
#pragma unroll
        for (int j = 0; j < 4; j++)
          acc[i][j] = MFMA16(av[i], bv[j], acc[i][j]);
      __builtin_amdgcn_s_setprio(0);
    }
  }

#pragma unroll
  for (int i = 0; i < 4; i++) {
    int rbase = row0 + wr * 64 + i * 16 + ((lane >> 4) * 4);
#pragma unroll
    for (int j = 0; j < 4; j++) {
      int c = col0 + wc * 64 + j * 16 + (lane & 15);
#pragma unroll
      for (int q = 0; q < 4; q++)
        Out[(long)(rbase + q) * ldc + c] = acc[i][j][q];
    }
  }
}

// ---------------- weighted combine of the two expert outputs -> bf16 ----------------
__global__ void combine_kernel(const float* __restrict__ Opair, const float* __restrict__ pr,
                               ushort* __restrict__ Cb) {
  const long n4 = (8L * 512 * 512) / 4;
  long stride = (long)gridDim.x * blockDim.x;
  for (long g = (long)blockIdx.x * blockDim.x + threadIdx.x; g < n4; g += stride) {
    long e = g * 4;
    int b = (int)(e >> 18);           // 512*512 = 2^18 per batch
    long r4 = (e & 262143) >> 2;
    float4 a = ((const float4*)(Opair + ((long)(2 * b) << 18)))[r4];
    float4 c = ((const float4*)(Opair + ((long)(2 * b + 1) << 18)))[r4];
    float p0 = pr[2 * b], p1 = pr[2 * b + 1];
    ((ushort4*)Cb)[g] = make_ushort4(f2bf(p0 * a.x + p1 * c.x), f2bf(p0 * a.y + p1 * c.y),
                                     f2bf(p0 * a.z + p1 * c.z), f2bf(p0 * a.w + p1 * c.w));
  }
}

extern "C" void kernel_launch(void* const* d_in, const int* in_sizes, int n_in,
                              void* d_out, int out_size, void* d_ws, size_t ws_size,
                              hipStream_t stream) {
  const float* hidden = (const float*)d_in[0];   // [8,512,512]
  const float* eprobs = (const float*)d_in[1];   // [8,16]
  const float* Wg     = (const float*)d_in[2];   // [16,2048,512]
  const float* Wu     = (const float*)d_in[3];   // [16,2048,512]
  const float* Wd     = (const float*)d_in[4];   // [16,512,2048]
  const float* Wout   = (const float*)d_in[5];   // [32000,512]
  float* out = (float*)d_out;                    // [8,512,32000] f32

  char* ws = (char*)d_ws;
  int*    t_ids = (int*)ws;                    // 16 ints
  float*  t_pr  = (float*)(ws + 64);           // 16 floats
  ushort* h_bf  = (ushort*)(ws + 256);         // 8*512*512
  ushort* wg_bf = h_bf  + 2097152L;            // 16*2048*512
  ushort* wu_bf = wg_bf + 16777216L;
  ushort* wd_bf = wu_bf + 16777216L;
  ushort* wo_bf = wd_bf + 16777216L;           // 32000*512
  ushort* Gbuf  = wo_bf + 16384000L;           // 16*512*2048 bf16
  float*  Opair = (float*)(Gbuf + 16777216L);  // 16*512*512 f32
  ushort* Cb    = (ushort*)(Opair + 4194304L); // 8*512*512 bf16

  hipLaunchKernelGGL(cvt_kernel, dim3(2048), dim3(256), 0, stream, hidden, h_bf, 2097152L / 4);
  hipLaunchKernelGGL(cvt_kernel, dim3(4096), dim3(256), 0, stream, Wg, wg_bf, 16777216L / 4);
  hipLaunchKernelGGL(cvt_kernel, dim3(4096), dim3(256), 0, stream, Wu, wu_bf, 16777216L / 4);
  hipLaunchKernelGGL(cvt_kernel, dim3(4096), dim3(256), 0, stream, Wd, wd_bf, 16777216L / 4);
  hipLaunchKernelGGL(cvt_kernel, dim3(4096), dim3(256), 0, stream, Wout, wo_bf, 16384000L / 4);
  hipLaunchKernelGGL(topk_kernel, dim3(1), dim3(64), 0, stream, eprobs, t_ids, t_pr);

  // gate/up fused: 512 blocks x 512 threads (BM=256, BN=128, dual-B)
  hipLaunchKernelGGL(gateup256, dim3(512), dim3(512), 0, stream,
                     h_bf, wg_bf, wu_bf, t_ids, Gbuf);
  // down: C[p][s,h] = G[p] x Wd[eid]^T   (K = 2048)
  hipLaunchKernelGGL(gemm_bt_f32, dim3(4, 4, 16), dim3(256), 0, stream,
                     Gbuf, (long)512 * 2048, wd_bf, (long)512 * 2048, t_ids,
                     Opair, (long)512 * 512, 2048, 512);
  hipLaunchKernelGGL(combine_kernel, dim3(1024), dim3(256), 0, stream, Opair, t_pr, Cb);
  // output projection: [4096,512] x [32000,512]^T  (K = 512), 2000 blocks x 512 thr
  hipLaunchKernelGGL(gemm256_final, dim3(2000), dim3(512), 0, stream,
                     Cb, wo_bf, out);
}

// Round 3
// 441.900 us; speedup vs baseline: 1.1273x; 1.0009x over previous
//
#include <hip/hip_runtime.h>
#include <hip/hip_bf16.h>
#include <cstdint>

typedef __attribute__((ext_vector_type(8))) short bf16x8;
typedef __attribute__((ext_vector_type(4))) float f32x4;

#define MFMA16(a, b, c) __builtin_amdgcn_mfma_f32_16x16x32_bf16((a), (b), (c), 0, 0, 0)

__device__ __forceinline__ ushort f2bf(float x) {
  union { float f; uint32_t u; } c; c.f = x;
  uint32_t r = (c.u + 0x7FFFu + ((c.u >> 16) & 1u)) >> 16;
  return (ushort)r;
}

__device__ __forceinline__ void gload_lds16(const ushort* g, ushort* l) {
  __builtin_amdgcn_global_load_lds((__attribute__((address_space(1))) void*)g,
                                   (__attribute__((address_space(3))) void*)l, 16, 0, 0);
}

// ---- BK=64 staging (128B rows), swizzle ((r&7)<<4): 2-way (free) on read ----
template <int NW, int INSTR>
__device__ __forceinline__ void stageT(const ushort* __restrict__ tileBase, int ld,
                                       ushort* lds, int wid, int lane) {
#pragma unroll
  for (int q = 0; q < INSTR; q++) {
    int r = (wid * INSTR + q) * 8 + (lane >> 3);
    int cb = ((lane & 7) * 16) ^ ((r & 7) << 4);
    gload_lds16(tileBase + (long)r * ld + (cb >> 1), lds + (wid * INSTR + q) * 512);
  }
}

__device__ __forceinline__ bf16x8 frag_read(const ushort* lds, int r, int kb) {
  int off = r * 128 + (kb ^ ((r & 7) << 4));
  return *(const bf16x8*)((const char*)lds + off);
}

// ---- BK=32 staging (64B rows), swizzle x=((r&3)^((r>>2)&3))<<4: 2-way on read ----
template <int NW, int INSTR>
__device__ __forceinline__ void stage32(const ushort* __restrict__ tileBase, int ld,
                                        ushort* lds, int wid, int lane) {
#pragma unroll
  for (int q = 0; q < INSTR; q++) {
    int r = (wid * INSTR + q) * 16 + (lane >> 2);
    int x = (((r & 3) ^ ((r >> 2) & 3)) << 4);
    int cb = ((lane & 3) * 16) ^ x;
    gload_lds16(tileBase + (long)r * ld + (cb >> 1), lds + (wid * INSTR + q) * 512);
  }
}

__device__ __forceinline__ bf16x8 frag_read32(const ushort* lds, int r, int kb) {
  int x = (((r & 3) ^ ((r >> 2) & 3)) << 4);
  int off = r * 64 + (kb ^ x);
  return *(const bf16x8*)((const char*)lds + off);
}

// ---------------- f32 -> bf16: hidden + Wout in one launch ----------------
__global__ void cvt_rest(const float* __restrict__ hidden, const float* __restrict__ wout,
                         ushort* __restrict__ h_bf, ushort* __restrict__ wo_bf) {
  const long h4 = 2097152L / 4, w4 = 16384000L / 4, n4 = h4 + w4;
  long stride = (long)gridDim.x * blockDim.x;
  for (long g = (long)blockIdx.x * blockDim.x + threadIdx.x; g < n4; g += stride) {
    if (g < h4) {
      float4 v = ((const float4*)hidden)[g];
      ((ushort4*)h_bf)[g] = make_ushort4(f2bf(v.x), f2bf(v.y), f2bf(v.z), f2bf(v.w));
    } else {
      long g2 = g - h4;
      float4 v = ((const float4*)wout)[g2];
      ((ushort4*)wo_bf)[g2] = make_ushort4(f2bf(v.x), f2bf(v.y), f2bf(v.z), f2bf(v.w));
    }
  }
}

// ---------------- top-k (k=2) + selected-expert mask ----------------
__global__ void topk_kernel(const float* __restrict__ probs, int* __restrict__ ids,
                            float* __restrict__ pr, int* __restrict__ sel) {
  int t = threadIdx.x;
  if (t < 16) sel[t] = 0;
  __syncthreads();
  if (t < 8) {
    const float* p = probs + t * 16;
    float v0 = -1e30f, v1 = -1e30f; int i0 = 0, i1 = 0;
    for (int e = 0; e < 16; e++) {
      float v = p[e];
      if (v > v0) { v1 = v0; i1 = i0; v0 = v; i0 = e; }
      else if (v > v1) { v1 = v; i1 = e; }
    }
    float s = 1.0f / (v0 + v1 + 1e-8f);
    ids[t * 2 + 0] = i0; ids[t * 2 + 1] = i1;
    pr[t * 2 + 0] = v0 * s; pr[t * 2 + 1] = v1 * s;
    sel[i0] = 1; sel[i1] = 1;
  }
}

// ---------------- convert only SELECTED experts of Wg/Wu/Wd ----------------
__global__ void cvt_experts(const float* __restrict__ Wg, const float* __restrict__ Wu,
                            const float* __restrict__ Wd, const int* __restrict__ sel,
                            ushort* __restrict__ wg_bf, ushort* __restrict__ wu_bf,
                            ushort* __restrict__ wd_bf) {
  const int e = blockIdx.y & 15, m = blockIdx.y >> 4;
  if (!sel[e]) return;
  const float* src = (m == 0 ? Wg : (m == 1 ? Wu : Wd)) + (long)e * 1048576L;
  ushort* dst = (m == 0 ? wg_bf : (m == 1 ? wu_bf : wd_bf)) + (long)e * 1048576L;
  const long n4 = 1048576L / 4;
  long stride = (long)gridDim.x * blockDim.x;
  for (long g = (long)blockIdx.x * blockDim.x + threadIdx.x; g < n4; g += stride) {
    float4 v = ((const float4*)src)[g];
    ((ushort4*)dst)[g] = make_ushort4(f2bf(v.x), f2bf(v.y), f2bf(v.z), f2bf(v.w));
  }
}

// ---------------- fused gate/up, BM=256 x BN=128, dual-B, 8 waves ----------------
__global__ __launch_bounds__(512, 2) void gateup256(
    const ushort* __restrict__ Hb, const ushort* __restrict__ Wg,
    const ushort* __restrict__ Wu, const int* __restrict__ ids,
    ushort* __restrict__ G) {
  constexpr int Hd = 512, I = 2048, S = 512, NT = Hd / 64;
  __shared__ ushort As[2][256 * 64], B1s[2][128 * 64], B2s[2][128 * 64];  // 128 KiB

  int wg = blockIdx.x;
  int swz = (wg & 7) * 64 + (wg >> 3);
  int p = swz >> 5;
  int r5 = swz & 31;
  int rowT = r5 & 1, colT = r5 >> 1;
  const int b = p >> 1, eid = ids[p];
  const int row0 = rowT * 256, col0 = colT * 128;
  const ushort* Ab  = Hb + (long)b * S * Hd + (long)row0 * Hd;
  const ushort* B1b = Wg + (long)eid * I * Hd + (long)col0 * Hd;
  const ushort* B2b = Wu + (long)eid * I * Hd + (long)col0 * Hd;

  const int tid = threadIdx.x, wid = tid >> 6, lane = tid & 63;
  const int wr = wid >> 2, wc = wid & 3;   // wave tile: 128 rows x 32 cols

  f32x4 acc1[8][2] = {};
  f32x4 acc2[8][2] = {};

  stageT<8, 4>(Ab, Hd, As[0], wid, lane);
  stageT<8, 2>(B1b, Hd, B1s[0], wid, lane);
  stageT<8, 2>(B2b, Hd, B2s[0], wid, lane);

  for (int kt = 0; kt < NT; kt++) {
    __syncthreads();
    const int cur = kt & 1;
    const ushort* as = As[cur];
    const ushort* b1 = B1s[cur];
    const ushort* b2 = B2s[cur];
    if (kt + 1 < NT) stageT<8, 4>(Ab + (kt + 1) * 64, Hd, As[cur ^ 1], wid, lane);
#pragma unroll
    for (int ks = 0; ks < 2; ks++) {
      const int kb = ks * 64 + ((lane >> 4) * 16);
      bf16x8 av[8];
#pragma unroll
      for (int i = 0; i < 8; i++) av[i] = frag_read(as, wr * 128 + i * 16 + (lane & 15), kb);
      if (ks == 0 && kt + 1 < NT) {
        stageT<8, 2>(B1b + (kt + 1) * 64, Hd, B1s[cur ^ 1], wid, lane);
        stageT<8, 2>(B2b + (kt + 1) * 64, Hd, B2s[cur ^ 1], wid, lane);
      }
      bf16x8 b1v[2], b2v[2];
#pragma unroll
      for (int j = 0; j < 2; j++) b1v[j] = frag_read(b1, wc * 32 + j * 16 + (lane & 15), kb);
      __builtin_amdgcn_s_setprio(1);
#pragma unroll
      for (int i = 0; i < 8; i++)
#pragma unroll
        for (int j = 0; j < 2; j++) acc1[i][j] = MFMA16(av[i], b1v[j], acc1[i][j]);
      __builtin_amdgcn_s_setprio(0);
#pragma unroll
      for (int j = 0; j < 2; j++) b2v[j] = frag_read(b2, wc * 32 + j * 16 + (lane & 15), kb);
      __builtin_amdgcn_s_setprio(1);
#pragma unroll
      for (int i = 0; i < 8; i++)
#pragma unroll
        for (int j = 0; j < 2; j++) acc2[i][j] = MFMA16(av[i], b2v[j], acc2[i][j]);
      __builtin_amdgcn_s_setprio(0);
    }
  }

  ushort* Gout = G + (long)p * S * I;
#pragma unroll
  for (int i = 0; i < 8; i++) {
    int r = row0 + wr * 128 + i * 16 + ((lane >> 4) * 4);
#pragma unroll
    for (int j = 0; j < 2; j++) {
      int c = col0 + wc * 32 + j * 16 + (lane & 15);
#pragma unroll
      for (int q = 0; q < 4; q++) {
        float g = acc1[i][j][q], u = acc2[i][j][q];
        float sg = g / (1.0f + __expf(-g));
        Gout[(long)(r + q) * I + c] = f2bf(sg * u);
      }
    }
  }
}

// ---------------- fused down GEMM + weighted combine -> bf16 Cb ----------------
// Per batch b: acc = G[2b] x Wd[e0]^T; acc *= p0/p1; acc += G[2b+1] x Wd[e1]^T;
// out = p1 * acc  ==  p0*out0 + p1*out1. (error bounded by p1*|B| when p1 tiny)
__global__ __launch_bounds__(256) void down_fused(
    const ushort* __restrict__ G, const ushort* __restrict__ Wd,
    const int* __restrict__ ids, const float* __restrict__ pr,
    ushort* __restrict__ Cb) {
  constexpr int I = 2048, Hd = 512, S = 512, NT = 64;
  const int b = blockIdx.z;
  const int row0 = blockIdx.x * 128, col0 = blockIdx.y * 64;
  __shared__ ushort As[2][128 * 64], Bs[2][64 * 64];  // 48 KiB
  const int tid = threadIdx.x, wid = tid >> 6, lane = tid & 63;
  const int wr = wid >> 1, wc = wid & 1;   // wave 64 x 32
  const int e0 = ids[2 * b], e1 = ids[2 * b + 1];
  const float p0 = pr[2 * b], p1 = pr[2 * b + 1];
  const ushort* A0 = G + ((long)(2 * b) * S + row0) * I;
  const ushort* A1 = G + ((long)(2 * b + 1) * S + row0) * I;
  const ushort* B0 = Wd + ((long)e0 * Hd + col0) * I;
  const ushort* B1 = Wd + ((long)e1 * Hd + col0) * I;

  f32x4 acc[4][2] = {};
  stageT<4, 4>(A0, I, As[0], wid, lane);
  stageT<4, 2>(B0, I, Bs[0], wid, lane);

  for (int t = 0; t < NT; t++) {
    __syncthreads();
    const int cur = t & 1;
    if (t + 1 < NT) {
      int t2 = t + 1;
      const ushort* An = (t2 < 32 ? A0 + t2 * 64 : A1 + (t2 - 32) * 64);
      const ushort* Bn = (t2 < 32 ? B0 + t2 * 64 : B1 + (t2 - 32) * 64);
      stageT<4, 4>(An, I, As[cur ^ 1], wid, lane);
      stageT<4, 2>(Bn, I, Bs[cur ^ 1], wid, lane);
    }
    if (t == 32) {
      float ratio = p0 / p1;
#pragma unroll
      for (int i = 0; i < 4; i++)
#pragma unroll
        for (int j = 0; j < 2; j++) acc[i][j] *= ratio;
    }
#pragma unroll
    for (int ks = 0; ks < 2; ks++) {
      const int kb = ks * 64 + ((lane >> 4) * 16);
      bf16x8 av[4], bv[2];
#pragma unroll
      for (int i = 0; i < 4; i++) av[i] = frag_read(As[cur], wr * 64 + i * 16 + (lane & 15), kb);
#pragma unroll
      for (int j = 0; j < 2; j++) bv[j] = frag_read(Bs[cur], wc * 32 + j * 16 + (lane & 15), kb);
      __builtin_amdgcn_s_setprio(1);
#pragma unroll
      for (int i = 0; i < 4; i++)
#pragma unroll
        for (int j = 0; j < 2; j++) acc[i][j] = MFMA16(av[i], bv[j], acc[i][j]);
      __builtin_amdgcn_s_setprio(0);
    }
  }

  ushort* Co = Cb + ((long)b * S + row0) * Hd + col0;
#pragma unroll
  for (int i = 0; i < 4; i++) {
    int r = wr * 64 + i * 16 + ((lane >> 4) * 4);
#pragma unroll
    for (int j = 0; j < 2; j++) {
      int c = wc * 32 + j * 16 + (lane & 15);
#pragma unroll
      for (int q = 0; q < 4; q++)
        Co[(long)(r + q) * Hd + c] = f2bf(p1 * acc[i][j][q]);
    }
  }
}

// ---------------- final projection: 256x128 tile, 4 waves, BK=32, 2 blocks/CU ----------------
__global__ __launch_bounds__(256, 2) void gemm_final(
    const ushort* __restrict__ A,   // [4096][512] bf16 (combined)
    const ushort* __restrict__ B,   // [32000][512] bf16 (Wout)
    float* __restrict__ Out) {      // [4096][32000] f32
  constexpr int K = 512, NT = 16, LDC = 32000;
  __shared__ ushort As[2][256 * 32], Bs[2][128 * 32];  // 48 KiB -> 2 blocks/CU

  int wg = blockIdx.x;                    // 4000 blocks, 4000 % 8 == 0
  int swz = (wg & 7) * 500 + (wg >> 3);
  const int colT = swz / 16, rowT = swz % 16;   // group by colT for B L2 reuse
  const int row0 = rowT * 256, col0 = colT * 128;

  const int tid = threadIdx.x, wid = tid >> 6, lane = tid & 63;
  const int wr = wid >> 1, wc = wid & 1;   // wave tile: 128 rows x 64 cols

  const ushort* Ab = A + (long)row0 * K;
  const ushort* Bb = B + (long)col0 * K;
  f32x4 acc[8][4] = {};

  stage32<4, 4>(Ab, K, As[0], wid, lane);
  stage32<4, 2>(Bb, K, Bs[0], wid, lane);

  for (int kt = 0; kt < NT; kt++) {
    __syncthreads();
    const int cur = kt & 1;
    if (kt + 1 < NT) {
      stage32<4, 4>(Ab + (kt + 1) * 32, K, As[cur ^ 1], wid, lane);
      stage32<4, 2>(Bb + (kt + 1) * 32, K, Bs[cur ^ 1], wid, lane);
    }
    const int kb = (lane >> 4) * 16;
    bf16x8 bv[4];
#pragma unroll
    for (int j = 0; j < 4; j++) bv[j] = frag_read32(Bs[cur], wc * 64 + j * 16 + (lane & 15), kb);
#pragma unroll
    for (int i = 0; i < 8; i++) {
      bf16x8 a = frag_read32(As[cur], wr * 128 + i * 16 + (lane & 15), kb);
      __builtin_amdgcn_s_setprio(1);
#pragma unroll
      for (int j = 0; j < 4; j++) acc[i][j] = MFMA16(a, bv[j], acc[i][j]);
      __builtin_amdgcn_s_setprio(0);
    }
  }

#pragma unroll
  for (int i = 0; i < 8; i++) {
    int r = row0 + wr * 128 + i * 16 + ((lane >> 4) * 4);
#pragma unroll
    for (int j = 0; j < 4; j++) {
      int c = col0 + wc * 64 + j * 16 + (lane & 15);
#pragma unroll
      for (int q = 0; q < 4; q++)
        Out[(long)(r + q) * LDC + c] = acc[i][j][q];
    }
  }
}

extern "C" void kernel_launch(void* const* d_in, const int* in_sizes, int n_in,
                              void* d_out, int out_size, void* d_ws, size_t ws_size,
                              hipStream_t stream) {
  const float* hidden = (const float*)d_in[0];   // [8,512,512]
  const float* eprobs = (const float*)d_in[1];   // [8,16]
  const float* Wg     = (const float*)d_in[2];   // [16,2048,512]
  const float* Wu     = (const float*)d_in[3];   // [16,2048,512]
  const float* Wd     = (const float*)d_in[4];   // [16,512,2048]
  const float* Wout   = (const float*)d_in[5];   // [32000,512]
  float* out = (float*)d_out;                    // [8,512,32000] f32

  char* ws = (char*)d_ws;
  int*    t_ids = (int*)ws;                    // 16 ints
  float*  t_pr  = (float*)(ws + 64);           // 16 floats
  int*    t_sel = (int*)(ws + 128);            // 16 ints
  ushort* h_bf  = (ushort*)(ws + 256);         // 8*512*512
  ushort* wg_bf = h_bf  + 2097152L;            // 16*2048*512
  ushort* wu_bf = wg_bf + 16777216L;
  ushort* wd_bf = wu_bf + 16777216L;
  ushort* wo_bf = wd_bf + 16777216L;           // 32000*512
  ushort* Gbuf  = wo_bf + 16384000L;           // 16*512*2048 bf16
  ushort* Cb    = Gbuf  + 16777216L;           // 8*512*512 bf16

  hipLaunchKernelGGL(topk_kernel, dim3(1), dim3(64), 0, stream, eprobs, t_ids, t_pr, t_sel);
  hipLaunchKernelGGL(cvt_rest, dim3(4096), dim3(256), 0, stream, hidden, Wout, h_bf, wo_bf);
  hipLaunchKernelGGL(cvt_experts, dim3(256, 48), dim3(256), 0, stream,
                     Wg, Wu, Wd, t_sel, wg_bf, wu_bf, wd_bf);

  // gate/up fused: 512 blocks x 512 threads (BM=256, BN=128, dual-B)
  hipLaunchKernelGGL(gateup256, dim3(512), dim3(512), 0, stream,
                     h_bf, wg_bf, wu_bf, t_ids, Gbuf);
  // down + combine fused: grid (S/128, H/64, B) = (4, 8, 8) = 256 blocks
  hipLaunchKernelGGL(down_fused, dim3(4, 8, 8), dim3(256), 0, stream,
                     Gbuf, wd_bf, t_ids, t_pr, Cb);
  // output projection: [4096,512] x [32000,512]^T, 4000 blocks x 256 thr, 2 blocks/CU
  hipLaunchKernelGGL(gemm_final, dim3(4000), dim3(256), 0, stream, Cb, wo_bf, out);
}